// Round 1
// baseline (189.081 us; speedup 1.0000x reference)
//
#include <hip/hip_runtime.h>
#include <math.h>

// IDMForwardSim R9: dual batch-group per block (NB=32). Each wave carries TWO
// independent LSTM recurrences (batches b0g..+15 and b0g+16..+31) so group-B
// MFMAs/LDS-reads interleave with group-A transcendental gate math in one
// instruction stream — deterministic latency hiding instead of relying on the
// stochastic phase of a second co-resident block. 256 blocks x 448 thr
// (7 waves, 1 block/CU). One barrier per step now advances 32 batches.
// Weight fragments (wb) are shared by both chains; only acc/state duplicate.

#define B_TOT 8192
#define T_STEPS 40
#define NB 32

typedef _Float16 f16;
typedef f16 f16x8 __attribute__((ext_vector_type(8)));
typedef float f32x4 __attribute__((ext_vector_type(4)));

__device__ __forceinline__ float rcpf(float x) { return __builtin_amdgcn_rcpf(x); }
__device__ __forceinline__ float ex2(float x)  { return __builtin_amdgcn_exp2f(x); }
__device__ __forceinline__ float sigf(float x)  { return rcpf(1.f + ex2(-1.44269504f * x)); }
__device__ __forceinline__ float tanhf_(float x){ return fmaf(-2.f, rcpf(1.f + ex2(2.88539008f * x)), 1.f); }

// ws layout (bytes): whb f16[65536] @0 | wxb f16[65536] @131072 | bp f32[512] @262144

__global__ __launch_bounds__(256) void idm_prep(
    const float* __restrict__ Wx, const float* __restrict__ Wh,
    const float* __restrict__ bvec, const float* __restrict__ attw,
    f16* __restrict__ whb, f16* __restrict__ wxb,
    float* __restrict__ bp)
{
  int i = blockIdx.x * 256 + threadIdx.x;  // 0..65535, i = k*512 + n (coalesced reads)
  int k = i >> 9, n = i & 511;
  int g = n >> 7, j128 = n & 127;
  float vh = 0.f, vx = 0.f;
  if (j128 < 100) {
    int col = g * 100 + j128;
    if (k < 100)      { vh = Wh[k * 400 + col]; vx = Wx[k * 400 + col]; }
    else if (k < 102) { vh = Wx[k * 400 + col]; }  // sdv rows folded into Wh-pad
  } else if (n == 100 && k < 100) {
    vh = attw[k];  // logit column: z[n=100] = h . att_W (Wx col / bias stay 0)
  }
  // dest B-frag index: tile=n>>4, kf=k>>5, l=((k>>3)&3)*16+(n&15), j=k&7
  int idx = (((n >> 4) * 4 + (k >> 5)) * 64 + (((k >> 3) & 3) * 16 + (n & 15))) * 8 + (k & 7);
  whb[idx] = (f16)vh;
  wxb[idx] = (f16)vx;
  if (i < 512) { int gg = i >> 7, jj = i & 127; bp[i] = (jj < 100) ? bvec[gg * 100 + jj] : 0.f; }
}

#define MM(z, a, g, kf) z = __builtin_amdgcn_mfma_f32_16x16x32_f16(a, wb[g][kf], z, 0, 0, 0)

__global__ __launch_bounds__(448, 2) void idm_main(
    const float* __restrict__ z_att,
    const float* __restrict__ linear_W,
    const float* __restrict__ linear_b,
    const float* __restrict__ sdv_acts,
    const f16* __restrict__ whb, const f16* __restrict__ wxb,
    const float* __restrict__ bp,
    const float* __restrict__ idm_params,
    const float* __restrict__ idm_s,
    const float* __restrict__ att_b,
    const float* __restrict__ noise_f,
    const float* __restrict__ noise_m,
    float* __restrict__ out)
{
  __shared__ f16   hS[2][2][16][136];    // [grp][buf][batch][k] 0..99 h, 100..101 sdv, pad 0
  __shared__ f16   sdvS[T_STEPS][32][2];
  __shared__ float logitS[T_STEPS][32];
  __shared__ float sS[32][T_STEPS][6];   // idm_s fields 1,2,4,5,6,7
  __shared__ float nS[2][T_STEPS][32];   // noise_f / noise_m
  __shared__ float accS[2][32][T_STEPS]; // act, att

  const int tid = threadIdx.x;
  const int w  = tid >> 6;   // 0..6 j-tile
  const int l  = tid & 63;
  const int lr = l & 15;
  const int lq = l >> 4;
  const int b0g = blockIdx.x * NB;
  const int jcol = 16 * w + lr;

  // zero hS (pad rows must stay exact 0): 2*2*16*136 f16 = 4352 dwords
  for (int idx = tid; idx < 4352; idx += 448) ((unsigned*)hS)[idx] = 0u;
  // coalesced staging: sdv (2560 f), idm_s fields (10240 f), noise (2560 f)
  for (int idx = tid; idx < 2560; idx += 448) {
    float v = sdv_acts[(size_t)b0g * 80 + idx];
    int b = idx / 80, r = idx - b * 80;
    sdvS[r >> 1][b][r & 1] = (f16)v;
  }
  for (int idx = tid; idx < 10240; idx += 448) {
    int f = idx & 7;
    if (f != 0 && f != 3) {
      int b = idx / 320, rem = idx - b * 320, t = rem >> 3;
      sS[b][t][(f < 3) ? f - 1 : f - 2] = idm_s[(size_t)b0g * 320 + idx];
    }
  }
  for (int idx = tid; idx < 2560; idx += 448) {
    int which = idx >= 1280 ? 1 : 0;
    int r = idx - which * 1280;
    int t = r >> 5, i = r & 31;
    nS[which][t][i] = which ? noise_m[(size_t)t * B_TOT + b0g + i]
                            : noise_f[(size_t)t * B_TOT + b0g + i];
  }
  __syncthreads();

  // h0 = att_proj into hS[grp][0], 32 batches x 16 octs = 512 slots
  for (int s = tid; s < 512; s += 448) {
    int lb = s >> 4, oct = s & 15;
    float za[10];
    #pragma unroll
    for (int t2 = 0; t2 < 10; ++t2) za[t2] = z_att[(size_t)(b0g + lb) * 10 + t2];
    #pragma unroll
    for (int jj = 0; jj < 8; ++jj) {
      int j = oct * 8 + jj;
      if (j < 100) {
        float acc = linear_b[j];
        #pragma unroll
        for (int t2 = 0; t2 < 10; ++t2) acc = fmaf(za[t2], linear_W[t2 * 100 + j], acc);
        hS[lb >> 4][0][lb & 15][j] = (f16)acc;
      }
    }
  }
  if (tid < 64) hS[tid >> 5][0][(tid >> 1) & 15][100 + (tid & 1)] = sdvS[0][tid >> 1][tid & 1];
  __syncthreads();

  // Wx frags -> cxA/cxB (shared weights, per-group A-frags), then Wh frags
  f16x8 wb[4][4];
  #pragma unroll
  for (int g = 0; g < 4; ++g) {
    int tile = w + 8 * g;
    #pragma unroll
    for (int kf = 0; kf < 4; ++kf)
      wb[g][kf] = *(const f16x8*)(wxb + ((size_t)(tile * 4 + kf) * 64 + l) * 8);
  }
  f32x4 cxA[4], cxB[4];
  #pragma unroll
  for (int g = 0; g < 4; ++g) {
    float bpv = bp[(w + 8 * g) * 16 + lr];
    f32x4 c = {bpv, bpv, bpv, bpv};
    cxA[g] = c; cxB[g] = c;
  }
  #pragma unroll
  for (int kf = 0; kf < 4; ++kf) {
    f16x8 aA = *(const f16x8*)(&hS[0][0][lr][kf * 32 + lq * 8]);
    f16x8 aB = *(const f16x8*)(&hS[1][0][lr][kf * 32 + lq * 8]);
    #pragma unroll
    for (int g = 0; g < 4; ++g) {
      cxA[g] = __builtin_amdgcn_mfma_f32_16x16x32_f16(aA, wb[g][kf], cxA[g], 0, 0, 0);
      cxB[g] = __builtin_amdgcn_mfma_f32_16x16x32_f16(aB, wb[g][kf], cxB[g], 0, 0, 0);
    }
  }
  #pragma unroll
  for (int g = 0; g < 4; ++g) {
    int tile = w + 8 * g;
    #pragma unroll
    for (int kf = 0; kf < 4; ++kf)
      wb[g][kf] = *(const f16x8*)(whb + ((size_t)(tile * 4 + kf) * 64 + l) * 8);
  }

  float cstA[4], cstB[4];
  #pragma unroll
  for (int r = 0; r < 4; ++r) {
    cstA[r] = (float)hS[0][0][lq * 4 + r][jcol];
    cstB[r] = (float)hS[1][0][lq * 4 + r][jcol];
  }

  int p = 0;
  for (int t = 0; t < T_STEPS; ++t) {
    // A-frags for both groups
    f16x8 aA0 = *(const f16x8*)(&hS[0][p][lr][0  + lq * 8]);
    f16x8 aA1 = *(const f16x8*)(&hS[0][p][lr][32 + lq * 8]);
    f16x8 aA2 = *(const f16x8*)(&hS[0][p][lr][64 + lq * 8]);
    f16x8 aA3 = *(const f16x8*)(&hS[0][p][lr][96 + lq * 8]);
    f16x8 aB0 = *(const f16x8*)(&hS[1][p][lr][0  + lq * 8]);
    f16x8 aB1 = *(const f16x8*)(&hS[1][p][lr][32 + lq * 8]);
    f16x8 aB2 = *(const f16x8*)(&hS[1][p][lr][64 + lq * 8]);
    f16x8 aB3 = *(const f16x8*)(&hS[1][p][lr][96 + lq * 8]);
    f32x4 zA0 = cxA[0], zA1 = cxA[1], zA2 = cxA[2], zA3 = cxA[3];
    f32x4 zB0 = cxB[0], zB1 = cxB[1], zB2 = cxB[2], zB3 = cxB[3];
    // group A MFMAs
    MM(zA0,aA0,0,0); MM(zA1,aA0,1,0); MM(zA2,aA0,2,0); MM(zA3,aA0,3,0);
    MM(zA0,aA1,0,1); MM(zA1,aA1,1,1); MM(zA2,aA1,2,1); MM(zA3,aA1,3,1);
    MM(zA0,aA2,0,2); MM(zA1,aA2,1,2); MM(zA2,aA2,2,2); MM(zA3,aA2,3,2);
    MM(zA0,aA3,0,3); MM(zA1,aA3,1,3); MM(zA2,aA3,2,3); MM(zA3,aA3,3,3);
    // group B MFMAs (independent chain; scheduler overlaps with A's gates)
    MM(zB0,aB0,0,0); MM(zB1,aB0,1,0); MM(zB2,aB0,2,0); MM(zB3,aB0,3,0);
    MM(zB0,aB1,0,1); MM(zB1,aB1,1,1); MM(zB2,aB1,2,1); MM(zB3,aB1,3,1);
    MM(zB0,aB2,0,2); MM(zB1,aB2,1,2); MM(zB2,aB2,2,2); MM(zB3,aB2,3,2);
    MM(zB0,aB3,0,3); MM(zB1,aB3,1,3); MM(zB2,aB3,2,3); MM(zB3,aB3,3,3);

    // logit for output t-1: z col n=100 (tile 6 = wave 6 g=0, lane lr==4)
    if (w == 6 && t > 0 && lr == 4) {
      #pragma unroll
      for (int r = 0; r < 4; ++r) {
        logitS[t - 1][lq * 4 + r]      = zA0[r];
        logitS[t - 1][16 + lq * 4 + r] = zB0[r];
      }
    }

    // gates A: 4 elements/lane (batch=lq*4+r, j=jcol)
    #pragma unroll
    for (int r = 0; r < 4; ++r) {
      float si = sigf(zA0[r]);
      float sf = sigf(zA1[r]);
      float tg = tanhf_(zA2[r]);
      float so = sigf(zA3[r]);
      float cc = fmaf(sf, cstA[r], si * tg);
      float hh = so * tanhf_(cc);
      cstA[r] = cc;
      if (jcol < 100) hS[0][p ^ 1][lq * 4 + r][jcol] = (f16)hh;
    }
    // gates B
    #pragma unroll
    for (int r = 0; r < 4; ++r) {
      float si = sigf(zB0[r]);
      float sf = sigf(zB1[r]);
      float tg = tanhf_(zB2[r]);
      float so = sigf(zB3[r]);
      float cc = fmaf(sf, cstB[r], si * tg);
      float hh = so * tanhf_(cc);
      cstB[r] = cc;
      if (jcol < 100) hS[1][p ^ 1][lq * 4 + r][jcol] = (f16)hh;
    }
    if (t + 1 < T_STEPS && tid < 64)
      hS[tid >> 5][p ^ 1][(tid >> 1) & 15][100 + (tid & 1)] = sdvS[t + 1][tid >> 1][tid & 1];
    __syncthreads();  // single barrier per step (serves both groups)
    p ^= 1;
  }

  // final logit (t = T-1) from h^{(T)} in hS[grp][p]: 8 MFMA on wave 6's gate-0 tile
  if (w == 6) {
    f32x4 zLA = {0.f, 0.f, 0.f, 0.f}, zLB = {0.f, 0.f, 0.f, 0.f};
    #pragma unroll
    for (int kf = 0; kf < 4; ++kf) {
      f16x8 aA = *(const f16x8*)(&hS[0][p][lr][kf * 32 + lq * 8]);
      f16x8 aB = *(const f16x8*)(&hS[1][p][lr][kf * 32 + lq * 8]);
      zLA = __builtin_amdgcn_mfma_f32_16x16x32_f16(aA, wb[0][kf], zLA, 0, 0, 0);
      zLB = __builtin_amdgcn_mfma_f32_16x16x32_f16(aB, wb[0][kf], zLB, 0, 0, 0);
    }
    if (lr == 4) {
      #pragma unroll
      for (int r = 0; r < 4; ++r) {
        logitS[T_STEPS - 1][lq * 4 + r]      = zLA[r];
        logitS[T_STEPS - 1][16 + lq * 4 + r] = zLB[r];
      }
    }
  }
  __syncthreads();

  // ---- tail: per-batch ego/IDM chain, all per-step operands in LDS ----
  if (tid < 32) {
    int lb = tid;
    int b = b0g + lb;
    const float* P = idm_params + (size_t)b * 5;
    float des_v = P[0], des_tg = P[1], min_jx = P[2], max_a = P[3];
    float inv2s = 0.5f / sqrtf(max_a * P[4]);
    float inv_dv = rcpf(des_v);
    float ego_v = idm_s[(size_t)b * 320 + 0];
    float ego_x = idm_s[(size_t)b * 320 + 3];
    float attb = att_b[0];
    float act = 0.f;
    #pragma unroll 4
    for (int t = 0; t < T_STEPS; ++t) {
      float2 s01 = *(const float2*)&sS[lb][t][0];  // f_v, m_v
      float2 s23 = *(const float2*)&sS[lb][t][2];  // f_x, m_x
      float2 s45 = *(const float2*)&sS[lb][t][4];  // f_ex, m_ex
      float nf = nS[0][t][lb], nm = nS[1][t][lb];
      float lg = attb + logitS[t][lb];
      ego_v += act * 0.1f;
      ego_x += ego_v * 0.1f + act * 0.005f;
      float af_, am_;
      {
        float dx = fminf(fmaxf(s23.x - ego_x, 0.5f), 1000.f);
        float dg = min_jx + fmaxf(0.f, des_tg * ego_v + ego_v * (ego_v - s01.x) * inv2s);
        float r = ego_v * inv_dv; float r2 = r * r; float q = dg * rcpf(dx);
        af_ = fminf(fmaxf(max_a * (1.f - r2 * r2 - q * q), -3.f), 3.f);
      }
      {
        float dx = fminf(fmaxf(s23.y - ego_x, 0.5f), 1000.f);
        float dg = min_jx + fmaxf(0.f, des_tg * ego_v + ego_v * (ego_v - s01.y) * inv2s);
        float r = ego_v * inv_dv; float r2 = r * r; float q = dg * rcpf(dx);
        am_ = fminf(fmaxf(max_a * (1.f - r2 * r2 - q * q), -3.f), 3.f);
      }
      float ef2 = s45.x * af_ + (1.f - s45.x) * nf;
      float em2 = s45.y * am_ + (1.f - s45.y) * nm;
      float att = sigf(5.f * lg);
      act = (1.f - att) * ef2 + att * em2;
      accS[0][lb][t] = act;
      accS[1][lb][t] = att;
    }
  }
  __syncthreads();

  // coalesced output store: 1280 floats per output per block
  if (tid < 320) {
    f32x4 va = ((const f32x4*)&accS[0][0][0])[tid];
    f32x4 vt = ((const f32x4*)&accS[1][0][0])[tid];
    *(f32x4*)(out + (size_t)b0g * T_STEPS + tid * 4) = va;
    *(f32x4*)(out + (size_t)B_TOT * T_STEPS + (size_t)b0g * T_STEPS + tid * 4) = vt;
  }
}

extern "C" void kernel_launch(void* const* d_in, const int* in_sizes, int n_in,
                              void* d_out, int out_size, void* d_ws, size_t ws_size,
                              hipStream_t stream) {
  const float* z_att      = (const float*)d_in[0];
  const float* idm_params = (const float*)d_in[2];
  const float* idm_s      = (const float*)d_in[3];
  const float* sdv_acts   = (const float*)d_in[4];
  const float* linear_W   = (const float*)d_in[5];
  const float* linear_b   = (const float*)d_in[6];
  const float* lstm_Wx    = (const float*)d_in[7];
  const float* lstm_Wh    = (const float*)d_in[8];
  const float* lstm_b     = (const float*)d_in[9];
  const float* att_W      = (const float*)d_in[10];
  const float* att_b      = (const float*)d_in[11];
  const float* noise_f    = (const float*)d_in[12];
  const float* noise_m    = (const float*)d_in[13];
  float* out = (float*)d_out;

  f16*   whb = (f16*)d_ws;
  f16*   wxb = (f16*)((char*)d_ws + 131072);
  float* bp  = (float*)((char*)d_ws + 262144);

  idm_prep<<<256, 256, 0, stream>>>(lstm_Wx, lstm_Wh, lstm_b, att_W, whb, wxb, bp);
  idm_main<<<B_TOT / NB, 448, 0, stream>>>(z_att, linear_W, linear_b, sdv_acts,
                                           whb, wxb, bp,
                                           idm_params, idm_s, att_b,
                                           noise_f, noise_m, out);
}

// Round 2
// 180.340 us; speedup vs baseline: 1.0485x; 1.0485x over previous
//
#include <hip/hip_runtime.h>
#include <math.h>

// IDMForwardSim R10: revert to R8 topology (NB=16, 512 blocks, 2 blocks/CU =
// best measured residency; R9 proved NB=32 is grid-capped at 1 block/CU) and
// add an 8th wave that runs the per-batch ego/IDM tail chain IN-LOOP at lag 2
// (logit[t-1] is barrier-visible after step t, so wave 7 processes tail step
// t-2 during step t). This removes the ~8-10 Kcycle serial end-tail that ran
// on one half-wave while 13+ waves idled, and moves the per-step sdv top-up
// off the compute waves. 512 blocks x 512 thr (8 waves), one barrier/step.

#define B_TOT 8192
#define T_STEPS 40
#define NB 16

typedef _Float16 f16;
typedef f16 f16x8 __attribute__((ext_vector_type(8)));
typedef float f32x4 __attribute__((ext_vector_type(4)));

__device__ __forceinline__ float rcpf(float x) { return __builtin_amdgcn_rcpf(x); }
__device__ __forceinline__ float ex2(float x)  { return __builtin_amdgcn_exp2f(x); }
__device__ __forceinline__ float sigf(float x)  { return rcpf(1.f + ex2(-1.44269504f * x)); }
__device__ __forceinline__ float tanhf_(float x){ return fmaf(-2.f, rcpf(1.f + ex2(2.88539008f * x)), 1.f); }

// ws layout (bytes): whb f16[65536] @0 | wxb f16[65536] @131072 | bp f32[512] @262144

__global__ __launch_bounds__(256) void idm_prep(
    const float* __restrict__ Wx, const float* __restrict__ Wh,
    const float* __restrict__ bvec, const float* __restrict__ attw,
    f16* __restrict__ whb, f16* __restrict__ wxb,
    float* __restrict__ bp)
{
  int i = blockIdx.x * 256 + threadIdx.x;  // 0..65535, i = k*512 + n (coalesced reads)
  int k = i >> 9, n = i & 511;
  int g = n >> 7, j128 = n & 127;
  float vh = 0.f, vx = 0.f;
  if (j128 < 100) {
    int col = g * 100 + j128;
    if (k < 100)      { vh = Wh[k * 400 + col]; vx = Wx[k * 400 + col]; }
    else if (k < 102) { vh = Wx[k * 400 + col]; }  // sdv rows folded into Wh-pad
  } else if (n == 100 && k < 100) {
    vh = attw[k];  // logit column: z[n=100] = h . att_W (Wx col / bias stay 0)
  }
  // dest B-frag index: tile=n>>4, kf=k>>5, l=((k>>3)&3)*16+(n&15), j=k&7
  int idx = (((n >> 4) * 4 + (k >> 5)) * 64 + (((k >> 3) & 3) * 16 + (n & 15))) * 8 + (k & 7);
  whb[idx] = (f16)vh;
  wxb[idx] = (f16)vx;
  if (i < 512) { int gg = i >> 7, jj = i & 127; bp[i] = (jj < 100) ? bvec[gg * 100 + jj] : 0.f; }
}

#define MM(z, a, g, kf) z = __builtin_amdgcn_mfma_f32_16x16x32_f16(a, wb[g][kf], z, 0, 0, 0)

__global__ __launch_bounds__(512, 4) void idm_main(
    const float* __restrict__ z_att,
    const float* __restrict__ linear_W,
    const float* __restrict__ linear_b,
    const float* __restrict__ sdv_acts,
    const f16* __restrict__ whb, const f16* __restrict__ wxb,
    const float* __restrict__ bp,
    const float* __restrict__ idm_params,
    const float* __restrict__ idm_s,
    const float* __restrict__ att_b,
    const float* __restrict__ noise_f,
    const float* __restrict__ noise_m,
    float* __restrict__ out)
{
  __shared__ f16   hS[2][16][136];       // [buf][batch][k] 0..99 h, 100..101 sdv, pad 0
  __shared__ f16   sdvS[T_STEPS][16][2];
  __shared__ float logitS[T_STEPS][16];
  __shared__ float sS[16][T_STEPS][6];   // idm_s fields 1,2,4,5,6,7
  __shared__ float nS[2][T_STEPS][16];   // noise_f / noise_m
  __shared__ float accS[2][16][T_STEPS]; // act, att

  const int tid = threadIdx.x;
  const int w  = tid >> 6;   // 0..6 j-tile, 7 = tail wave
  const int l  = tid & 63;
  const int lr = l & 15;
  const int lq = l >> 4;
  const int b0g = blockIdx.x * NB;
  const int jcol = 16 * w + lr;

  // zero hS (pad rows must stay exact 0)
  for (int idx = tid; idx < 2176; idx += 512) ((unsigned*)hS)[idx] = 0u;
  // coalesced staging: sdv (1280 f), idm_s fields (5120 f), noise (1280 f)
  for (int idx = tid; idx < 1280; idx += 512) {
    float v = sdv_acts[(size_t)b0g * 80 + idx];
    int b = idx / 80, r = idx - b * 80;
    sdvS[r >> 1][b][r & 1] = (f16)v;
  }
  for (int idx = tid; idx < 5120; idx += 512) {
    int f = idx & 7;
    if (f != 0 && f != 3) {
      int b = idx / 320, rem = idx - b * 320, t = rem >> 3;
      sS[b][t][(f < 3) ? f - 1 : f - 2] = idm_s[(size_t)b0g * 320 + idx];
    }
  }
  for (int idx = tid; idx < 1280; idx += 512) {
    int which = idx >= 640 ? 1 : 0;
    int r = idx - which * 640;
    int t = r >> 4, i = r & 15;
    nS[which][t][i] = which ? noise_m[(size_t)t * B_TOT + b0g + i]
                            : noise_f[(size_t)t * B_TOT + b0g + i];
  }
  __syncthreads();

  // h0 = att_proj into hS[0]
  if (tid < 256) {
    int b = tid >> 4, oct = tid & 15;
    float za[10];
    #pragma unroll
    for (int t2 = 0; t2 < 10; ++t2) za[t2] = z_att[(b0g + b) * 10 + t2];
    #pragma unroll
    for (int jj = 0; jj < 8; ++jj) {
      int j = oct * 8 + jj;
      if (j < 100) {
        float acc = linear_b[j];
        #pragma unroll
        for (int t2 = 0; t2 < 10; ++t2) acc = fmaf(za[t2], linear_W[t2 * 100 + j], acc);
        hS[0][b][j] = (f16)acc;
      }
    }
  }
  if (tid < 32) hS[0][tid >> 1][100 + (tid & 1)] = sdvS[0][tid >> 1][tid & 1];
  __syncthreads();

  // compute waves: Wx frags -> cx, then Wh frags (loop-invariant in regs)
  f16x8 wb[4][4];
  f32x4 cx[4];
  float cst[4];
  if (w < 7) {
    #pragma unroll
    for (int g = 0; g < 4; ++g) {
      int tile = w + 8 * g;
      #pragma unroll
      for (int kf = 0; kf < 4; ++kf)
        wb[g][kf] = *(const f16x8*)(wxb + ((size_t)(tile * 4 + kf) * 64 + l) * 8);
    }
    #pragma unroll
    for (int g = 0; g < 4; ++g) {
      float bpv = bp[(w + 8 * g) * 16 + lr];
      f32x4 c = {bpv, bpv, bpv, bpv};
      cx[g] = c;
    }
    #pragma unroll
    for (int kf = 0; kf < 4; ++kf) {
      f16x8 a = *(const f16x8*)(&hS[0][lr][kf * 32 + lq * 8]);
      #pragma unroll
      for (int g = 0; g < 4; ++g)
        cx[g] = __builtin_amdgcn_mfma_f32_16x16x32_f16(a, wb[g][kf], cx[g], 0, 0, 0);
    }
    #pragma unroll
    for (int g = 0; g < 4; ++g) {
      int tile = w + 8 * g;
      #pragma unroll
      for (int kf = 0; kf < 4; ++kf)
        wb[g][kf] = *(const f16x8*)(whb + ((size_t)(tile * 4 + kf) * 64 + l) * 8);
    }
    #pragma unroll
    for (int r = 0; r < 4; ++r) cst[r] = (float)hS[0][lq * 4 + r][jcol];
  }

  // tail-wave state (wave 7, lanes 0..15)
  float des_v = 0.f, des_tg = 0.f, min_jx = 0.f, max_a = 0.f;
  float inv2s = 0.f, inv_dv = 0.f, ego_v = 0.f, ego_x = 0.f, attb = 0.f, actT = 0.f;
  if (w == 7 && l < NB) {
    int b = b0g + l;
    const float* P = idm_params + (size_t)b * 5;
    des_v = P[0]; des_tg = P[1]; min_jx = P[2]; max_a = P[3];
    inv2s = 0.5f / sqrtf(max_a * P[4]);
    inv_dv = rcpf(des_v);
    ego_v = idm_s[(size_t)b * 320 + 0];
    ego_x = idm_s[(size_t)b * 320 + 3];
    attb = att_b[0];
    actT = 0.f;
  }

  auto tail_step = [&](int tt) {
    float2 s01 = *(const float2*)&sS[l][tt][0];  // f_v, m_v
    float2 s23 = *(const float2*)&sS[l][tt][2];  // f_x, m_x
    float2 s45 = *(const float2*)&sS[l][tt][4];  // f_ex, m_ex
    float nf = nS[0][tt][l], nm = nS[1][tt][l];
    float lg = attb + logitS[tt][l];
    ego_v += actT * 0.1f;
    ego_x += ego_v * 0.1f + actT * 0.005f;
    float af_, am_;
    {
      float dx = fminf(fmaxf(s23.x - ego_x, 0.5f), 1000.f);
      float dg = min_jx + fmaxf(0.f, des_tg * ego_v + ego_v * (ego_v - s01.x) * inv2s);
      float r = ego_v * inv_dv; float r2 = r * r; float q = dg * rcpf(dx);
      af_ = fminf(fmaxf(max_a * (1.f - r2 * r2 - q * q), -3.f), 3.f);
    }
    {
      float dx = fminf(fmaxf(s23.y - ego_x, 0.5f), 1000.f);
      float dg = min_jx + fmaxf(0.f, des_tg * ego_v + ego_v * (ego_v - s01.y) * inv2s);
      float r = ego_v * inv_dv; float r2 = r * r; float q = dg * rcpf(dx);
      am_ = fminf(fmaxf(max_a * (1.f - r2 * r2 - q * q), -3.f), 3.f);
    }
    float ef2 = s45.x * af_ + (1.f - s45.x) * nf;
    float em2 = s45.y * am_ + (1.f - s45.y) * nm;
    float att = sigf(5.f * lg);
    actT = (1.f - att) * ef2 + att * em2;
    accS[0][l][tt] = actT;
    accS[1][l][tt] = att;
  };

  int p = 0;
  for (int t = 0; t < T_STEPS; ++t) {
    if (w < 7) {
      // A-frags for [h^{(t)}, sdv_t]
      f16x8 a0 = *(const f16x8*)(&hS[p][lr][0  + lq * 8]);
      f16x8 a1 = *(const f16x8*)(&hS[p][lr][32 + lq * 8]);
      f16x8 a2 = *(const f16x8*)(&hS[p][lr][64 + lq * 8]);
      f16x8 a3 = *(const f16x8*)(&hS[p][lr][96 + lq * 8]);
      f32x4 z0 = cx[0], z1 = cx[1], z2 = cx[2], z3 = cx[3];
      MM(z0,a0,0,0); MM(z1,a0,1,0); MM(z2,a0,2,0); MM(z3,a0,3,0);
      MM(z0,a1,0,1); MM(z1,a1,1,1); MM(z2,a1,2,1); MM(z3,a1,3,1);
      MM(z0,a2,0,2); MM(z1,a2,1,2); MM(z2,a2,2,2); MM(z3,a2,3,2);
      MM(z0,a3,0,3); MM(z1,a3,1,3); MM(z2,a3,2,3); MM(z3,a3,3,3);

      // logit for output t-1: z col n=100 (tile 6 = wave 6 g=0, lane lr==4)
      if (w == 6 && t > 0 && lr == 4) {
        #pragma unroll
        for (int r = 0; r < 4; ++r) logitS[t - 1][lq * 4 + r] = z0[r];
      }

      // gates: 4 elements/lane (batch=lq*4+r, j=jcol)
      #pragma unroll
      for (int r = 0; r < 4; ++r) {
        float si = sigf(z0[r]);
        float sf = sigf(z1[r]);
        float tg = tanhf_(z2[r]);
        float so = sigf(z3[r]);
        float cc = fmaf(sf, cst[r], si * tg);
        float hh = so * tanhf_(cc);
        cst[r] = cc;
        if (jcol < 100) hS[p ^ 1][lq * 4 + r][jcol] = (f16)hh;
      }
    } else {
      // wave 7: sdv top-up for t+1, then tail step t-2 (logit[t-2] is
      // barrier-visible since the end of step t-1)
      if (t + 1 < T_STEPS && l < 32)
        hS[p ^ 1][l >> 1][100 + (l & 1)] = sdvS[t + 1][l >> 1][l & 1];
      if (t >= 2 && l < NB) tail_step(t - 2);
    }
    __syncthreads();  // single barrier per step
    p ^= 1;
  }

  // final logit (t = T-1) from h^{(T)} in hS[p]: 4 MFMA on wave 6's gate-0 tile
  if (w == 6) {
    f32x4 zL = {0.f, 0.f, 0.f, 0.f};
    #pragma unroll
    for (int kf = 0; kf < 4; ++kf) {
      f16x8 a = *(const f16x8*)(&hS[p][lr][kf * 32 + lq * 8]);
      zL = __builtin_amdgcn_mfma_f32_16x16x32_f16(a, wb[0][kf], zL, 0, 0, 0);
    }
    if (lr == 4) {
      #pragma unroll
      for (int r = 0; r < 4; ++r) logitS[T_STEPS - 1][lq * 4 + r] = zL[r];
    }
  }
  // tail step 38 is already runnable (logit[38] visible since last loop barrier)
  if (w == 7 && l < NB) tail_step(T_STEPS - 2);
  __syncthreads();
  if (w == 7 && l < NB) tail_step(T_STEPS - 1);
  __syncthreads();

  // coalesced output store: 640 floats per output
  if (tid < 160) {
    f32x4 va = ((const f32x4*)&accS[0][0][0])[tid];
    f32x4 vt = ((const f32x4*)&accS[1][0][0])[tid];
    *(f32x4*)(out + (size_t)b0g * T_STEPS + tid * 4) = va;
    *(f32x4*)(out + (size_t)B_TOT * T_STEPS + (size_t)b0g * T_STEPS + tid * 4) = vt;
  }
}

extern "C" void kernel_launch(void* const* d_in, const int* in_sizes, int n_in,
                              void* d_out, int out_size, void* d_ws, size_t ws_size,
                              hipStream_t stream) {
  const float* z_att      = (const float*)d_in[0];
  const float* idm_params = (const float*)d_in[2];
  const float* idm_s      = (const float*)d_in[3];
  const float* sdv_acts   = (const float*)d_in[4];
  const float* linear_W   = (const float*)d_in[5];
  const float* linear_b   = (const float*)d_in[6];
  const float* lstm_Wx    = (const float*)d_in[7];
  const float* lstm_Wh    = (const float*)d_in[8];
  const float* lstm_b     = (const float*)d_in[9];
  const float* att_W      = (const float*)d_in[10];
  const float* att_b      = (const float*)d_in[11];
  const float* noise_f    = (const float*)d_in[12];
  const float* noise_m    = (const float*)d_in[13];
  float* out = (float*)d_out;

  f16*   whb = (f16*)d_ws;
  f16*   wxb = (f16*)((char*)d_ws + 131072);
  float* bp  = (float*)((char*)d_ws + 262144);

  idm_prep<<<256, 256, 0, stream>>>(lstm_Wx, lstm_Wh, lstm_b, att_W, whb, wxb, bp);
  idm_main<<<B_TOT / NB, 512, 0, stream>>>(z_att, linear_W, linear_b, sdv_acts,
                                           whb, wxb, bp,
                                           idm_params, idm_s, att_b,
                                           noise_f, noise_m, out);
}

// Round 5
// 178.496 us; speedup vs baseline: 1.0593x; 1.0103x over previous
//
#include <hip/hip_runtime.h>
#include <math.h>

// IDMForwardSim R11b: R11 with codegen hardening (pragma unroll 2 on t-loop,
// flattened tail guard) after two container failures on R11 — no algorithmic
// change. R8 topology (NB=16, 448 thr, 7 waves, 2 blocks/CU).
// Changes vs R8:
//  (1) tail-in-loop: per-batch ego/IDM chain on wave 0 lanes 0..15 at lag 2
//      (logit[t-2] barrier-visible), straight-line macro (no lambda/scratch).
//  (2) exp2 scale constants (1.4427 / 2.8854) pre-folded into weight/bias
//      columns in idm_prep (logit col n=100 unscaled).

#define B_TOT 8192
#define T_STEPS 40
#define NB 16

typedef _Float16 f16;
typedef f16 f16x8 __attribute__((ext_vector_type(8)));
typedef float f32x4 __attribute__((ext_vector_type(4)));

__device__ __forceinline__ float rcpf(float x) { return __builtin_amdgcn_rcpf(x); }
__device__ __forceinline__ float ex2(float x)  { return __builtin_amdgcn_exp2f(x); }
__device__ __forceinline__ float sigf(float x)  { return rcpf(1.f + ex2(-1.44269504f * x)); }
__device__ __forceinline__ float tanhf_(float x){ return fmaf(-2.f, rcpf(1.f + ex2(2.88539008f * x)), 1.f); }

// ws layout (bytes): whb f16[65536] @0 | wxb f16[65536] @131072 | bp f32[512] @262144

__global__ __launch_bounds__(256) void idm_prep(
    const float* __restrict__ Wx, const float* __restrict__ Wh,
    const float* __restrict__ bvec, const float* __restrict__ attw,
    f16* __restrict__ whb, f16* __restrict__ wxb,
    float* __restrict__ bp)
{
  int i = blockIdx.x * 256 + threadIdx.x;  // 0..65535, i = k*512 + n (coalesced reads)
  int k = i >> 9, n = i & 511;
  int g = n >> 7, j128 = n & 127;
  // pre-scale: sigmoid gates (zi,zf,zo) by log2(e), tanh gate (zg) by 2*log2(e)
  float sc = (g == 2) ? 2.88539008f : 1.44269504f;
  float vh = 0.f, vx = 0.f;
  if (j128 < 100) {
    int col = g * 100 + j128;
    if (k < 100)      { vh = Wh[k * 400 + col] * sc; vx = Wx[k * 400 + col] * sc; }
    else if (k < 102) { vh = Wx[k * 400 + col] * sc; }  // sdv rows folded into Wh-pad
  } else if (n == 100 && k < 100) {
    vh = attw[k];  // logit column stays UNSCALED (z[n=100] = h . att_W)
  }
  // dest B-frag index: tile=n>>4, kf=k>>5, l=((k>>3)&3)*16+(n&15), j=k&7
  int idx = (((n >> 4) * 4 + (k >> 5)) * 64 + (((k >> 3) & 3) * 16 + (n & 15))) * 8 + (k & 7);
  whb[idx] = (f16)vh;
  wxb[idx] = (f16)vx;
  if (i < 512) {
    int gg = i >> 7, jj = i & 127;
    float scb = (gg == 2) ? 2.88539008f : 1.44269504f;
    bp[i] = (jj < 100) ? bvec[gg * 100 + jj] * scb : 0.f;
  }
}

#define MM(z, a, g, kf) z = __builtin_amdgcn_mfma_f32_16x16x32_f16(a, wb[g][kf], z, 0, 0, 0)

// scratch-free tail step (wave 0, lanes 0..15; all state in plain locals)
#define TAIL_STEP(tt) {                                                        \
    int tt_ = (tt);                                                            \
    float2 s01 = *(const float2*)&sS[l][tt_][0];                               \
    float2 s23 = *(const float2*)&sS[l][tt_][2];                               \
    float2 s45 = *(const float2*)&sS[l][tt_][4];                               \
    float nf = nS[0][tt_][l], nm = nS[1][tt_][l];                              \
    float lg = attb + logitS[tt_][l];                                          \
    ego_v += actT * 0.1f;                                                      \
    ego_x += ego_v * 0.1f + actT * 0.005f;                                     \
    float dxf = fminf(fmaxf(s23.x - ego_x, 0.5f), 1000.f);                     \
    float dgf = min_jx + fmaxf(0.f, des_tg * ego_v + ego_v * (ego_v - s01.x) * inv2s); \
    float rr = ego_v * inv_dv; float rr2 = rr * rr;                            \
    float qf = dgf * rcpf(dxf);                                                \
    float af_ = fminf(fmaxf(max_a * (1.f - rr2 * rr2 - qf * qf), -3.f), 3.f);  \
    float dxm = fminf(fmaxf(s23.y - ego_x, 0.5f), 1000.f);                     \
    float dgm = min_jx + fmaxf(0.f, des_tg * ego_v + ego_v * (ego_v - s01.y) * inv2s); \
    float qm = dgm * rcpf(dxm);                                                \
    float am_ = fminf(fmaxf(max_a * (1.f - rr2 * rr2 - qm * qm), -3.f), 3.f);  \
    float ef2 = s45.x * af_ + (1.f - s45.x) * nf;                              \
    float em2 = s45.y * am_ + (1.f - s45.y) * nm;                              \
    float att = sigf(5.f * lg);                                                \
    actT = (1.f - att) * ef2 + att * em2;                                      \
    accS[0][l][tt_] = actT;                                                    \
    accS[1][l][tt_] = att;                                                     \
  }

__global__ __launch_bounds__(448, 4) void idm_main(
    const float* __restrict__ z_att,
    const float* __restrict__ linear_W,
    const float* __restrict__ linear_b,
    const float* __restrict__ sdv_acts,
    const f16* __restrict__ whb, const f16* __restrict__ wxb,
    const float* __restrict__ bp,
    const float* __restrict__ idm_params,
    const float* __restrict__ idm_s,
    const float* __restrict__ att_b,
    const float* __restrict__ noise_f,
    const float* __restrict__ noise_m,
    float* __restrict__ out)
{
  __shared__ f16   hS[2][16][136];       // [buf][batch][k] 0..99 h, 100..101 sdv, pad 0
  __shared__ f16   sdvS[T_STEPS][16][2];
  __shared__ float logitS[T_STEPS][16];
  __shared__ float sS[16][T_STEPS][6];   // idm_s fields 1,2,4,5,6,7
  __shared__ float nS[2][T_STEPS][16];   // noise_f / noise_m
  __shared__ float accS[2][16][T_STEPS]; // act, att

  const int tid = threadIdx.x;
  const int w  = tid >> 6;   // 0..6 j-tile
  const int l  = tid & 63;
  const int lr = l & 15;
  const int lq = l >> 4;
  const int b0g = blockIdx.x * NB;
  const int jcol = 16 * w + lr;
  const bool tail_lane = (tid < NB);  // wave 0, lanes 0..15

  // zero hS (pad rows must stay exact 0)
  for (int idx = tid; idx < 2176; idx += 448) ((unsigned*)hS)[idx] = 0u;
  // coalesced staging: sdv (1280 f), idm_s fields (5120 f), noise (1280 f)
  for (int idx = tid; idx < 1280; idx += 448) {
    float v = sdv_acts[(size_t)b0g * 80 + idx];
    int b = idx / 80, r = idx - b * 80;
    sdvS[r >> 1][b][r & 1] = (f16)v;
  }
  for (int idx = tid; idx < 5120; idx += 448) {
    int f = idx & 7;
    if (f != 0 && f != 3) {
      int b = idx / 320, rem = idx - b * 320, t = rem >> 3;
      sS[b][t][(f < 3) ? f - 1 : f - 2] = idm_s[(size_t)b0g * 320 + idx];
    }
  }
  for (int idx = tid; idx < 1280; idx += 448) {
    int which = idx >= 640 ? 1 : 0;
    int r = idx - which * 640;
    int t = r >> 4, i = r & 15;
    nS[which][t][i] = which ? noise_m[(size_t)t * B_TOT + b0g + i]
                            : noise_f[(size_t)t * B_TOT + b0g + i];
  }
  __syncthreads();

  // h0 = att_proj into hS[0]
  if (tid < 256) {
    int b = tid >> 4, oct = tid & 15;
    float za[10];
    #pragma unroll
    for (int t2 = 0; t2 < 10; ++t2) za[t2] = z_att[(b0g + b) * 10 + t2];
    #pragma unroll
    for (int jj = 0; jj < 8; ++jj) {
      int j = oct * 8 + jj;
      if (j < 100) {
        float acc = linear_b[j];
        #pragma unroll
        for (int t2 = 0; t2 < 10; ++t2) acc = fmaf(za[t2], linear_W[t2 * 100 + j], acc);
        hS[0][b][j] = (f16)acc;
      }
    }
  }
  if (tid < 32) hS[0][tid >> 1][100 + (tid & 1)] = sdvS[0][tid >> 1][tid & 1];
  __syncthreads();

  // Wx frags -> cx, then Wh frags (loop-invariant in regs)
  f16x8 wb[4][4];
  #pragma unroll
  for (int g = 0; g < 4; ++g) {
    int tile = w + 8 * g;
    #pragma unroll
    for (int kf = 0; kf < 4; ++kf)
      wb[g][kf] = *(const f16x8*)(wxb + ((size_t)(tile * 4 + kf) * 64 + l) * 8);
  }
  f32x4 cx[4];
  #pragma unroll
  for (int g = 0; g < 4; ++g) {
    float bpv = bp[(w + 8 * g) * 16 + lr];
    f32x4 c = {bpv, bpv, bpv, bpv};
    cx[g] = c;
  }
  #pragma unroll
  for (int kf = 0; kf < 4; ++kf) {
    f16x8 a = *(const f16x8*)(&hS[0][lr][kf * 32 + lq * 8]);
    #pragma unroll
    for (int g = 0; g < 4; ++g)
      cx[g] = __builtin_amdgcn_mfma_f32_16x16x32_f16(a, wb[g][kf], cx[g], 0, 0, 0);
  }
  #pragma unroll
  for (int g = 0; g < 4; ++g) {
    int tile = w + 8 * g;
    #pragma unroll
    for (int kf = 0; kf < 4; ++kf)
      wb[g][kf] = *(const f16x8*)(whb + ((size_t)(tile * 4 + kf) * 64 + l) * 8);
  }

  float cst[4];
  #pragma unroll
  for (int r = 0; r < 4; ++r) cst[r] = (float)hS[0][lq * 4 + r][jcol];

  // tail state (wave 0 lanes 0..15 only; plain locals, no lambda/scratch)
  float des_v = 1.f, des_tg = 0.f, min_jx = 0.f, max_a = 1.f;
  float inv2s = 0.f, inv_dv = 1.f, ego_v = 0.f, ego_x = 0.f, attb = 0.f, actT = 0.f;
  if (tail_lane) {
    int b = b0g + l;
    const float* P = idm_params + (size_t)b * 5;
    des_v = P[0]; des_tg = P[1]; min_jx = P[2]; max_a = P[3];
    inv2s = 0.5f / sqrtf(max_a * P[4]);
    inv_dv = rcpf(des_v);
    ego_v = idm_s[(size_t)b * 320 + 0];
    ego_x = idm_s[(size_t)b * 320 + 3];
    attb = att_b[0];
  }

  int p = 0;
  #pragma unroll 2
  for (int t = 0; t < T_STEPS; ++t) {
    // A-frags for [h^{(t)}, sdv_t]
    f16x8 a0 = *(const f16x8*)(&hS[p][lr][0  + lq * 8]);
    f16x8 a1 = *(const f16x8*)(&hS[p][lr][32 + lq * 8]);
    f16x8 a2 = *(const f16x8*)(&hS[p][lr][64 + lq * 8]);
    f16x8 a3 = *(const f16x8*)(&hS[p][lr][96 + lq * 8]);
    f32x4 z0 = cx[0], z1 = cx[1], z2 = cx[2], z3 = cx[3];
    MM(z0,a0,0,0); MM(z1,a0,1,0); MM(z2,a0,2,0); MM(z3,a0,3,0);
    MM(z0,a1,0,1); MM(z1,a1,1,1); MM(z2,a1,2,1); MM(z3,a1,3,1);
    MM(z0,a2,0,2); MM(z1,a2,1,2); MM(z2,a2,2,2); MM(z3,a2,3,2);
    MM(z0,a3,0,3); MM(z1,a3,1,3); MM(z2,a3,2,3); MM(z3,a3,3,3);

    // logit for output t-1: z col n=100 (tile 6 = wave 6 g=0, lane lr==4)
    if (w == 6 && t > 0 && lr == 4) {
      #pragma unroll
      for (int r = 0; r < 4; ++r) logitS[t - 1][lq * 4 + r] = z0[r];
    }

    // gates: 4 elements/lane (batch=lq*4+r, j=jcol); scale pre-folded into z
    #pragma unroll
    for (int r = 0; r < 4; ++r) {
      float si = rcpf(1.f + ex2(-z0[r]));
      float sf = rcpf(1.f + ex2(-z1[r]));
      float tg = fmaf(-2.f, rcpf(1.f + ex2(z2[r])), 1.f);
      float so = rcpf(1.f + ex2(-z3[r]));
      float cc = fmaf(sf, cst[r], si * tg);
      float hh = so * tanhf_(cc);
      cst[r] = cc;
      if (jcol < 100) hS[p ^ 1][lq * 4 + r][jcol] = (f16)hh;
    }
    if (t + 1 < T_STEPS && tid < 32)
      hS[p ^ 1][tid >> 1][100 + (tid & 1)] = sdvS[t + 1][tid >> 1][tid & 1];
    // wave 0 lanes 0..15: lag-2 tail step (logit[t-2] visible since end of
    // step t-1); serial latency hides under the other waves' gate math
    if (tail_lane && t >= 2) TAIL_STEP(t - 2);
    __syncthreads();  // single barrier per step
    p ^= 1;
  }

  // final logit (t = T-1) from h^{(T)} in hS[p]: 4 MFMA on wave 6's gate-0 tile
  if (w == 6) {
    f32x4 zL = {0.f, 0.f, 0.f, 0.f};
    #pragma unroll
    for (int kf = 0; kf < 4; ++kf) {
      f16x8 a = *(const f16x8*)(&hS[p][lr][kf * 32 + lq * 8]);
      zL = __builtin_amdgcn_mfma_f32_16x16x32_f16(a, wb[0][kf], zL, 0, 0, 0);
    }
    if (lr == 4) {
      #pragma unroll
      for (int r = 0; r < 4; ++r) logitS[T_STEPS - 1][lq * 4 + r] = zL[r];
    }
  }
  // tail step 38 runnable now (logit[38] visible since last loop barrier)
  if (tail_lane) TAIL_STEP(T_STEPS - 2);
  __syncthreads();
  if (tail_lane) TAIL_STEP(T_STEPS - 1);
  __syncthreads();

  // coalesced output store: 640 floats per output
  if (tid < 160) {
    f32x4 va = ((const f32x4*)&accS[0][0][0])[tid];
    f32x4 vt = ((const f32x4*)&accS[1][0][0])[tid];
    *(f32x4*)(out + (size_t)b0g * T_STEPS + tid * 4) = va;
    *(f32x4*)(out + (size_t)B_TOT * T_STEPS + (size_t)b0g * T_STEPS + tid * 4) = vt;
  }
}

extern "C" void kernel_launch(void* const* d_in, const int* in_sizes, int n_in,
                              void* d_out, int out_size, void* d_ws, size_t ws_size,
                              hipStream_t stream) {
  const float* z_att      = (const float*)d_in[0];
  const float* idm_params = (const float*)d_in[2];
  const float* idm_s      = (const float*)d_in[3];
  const float* sdv_acts   = (const float*)d_in[4];
  const float* linear_W   = (const float*)d_in[5];
  const float* linear_b   = (const float*)d_in[6];
  const float* lstm_Wx    = (const float*)d_in[7];
  const float* lstm_Wh    = (const float*)d_in[8];
  const float* lstm_b     = (const float*)d_in[9];
  const float* att_W      = (const float*)d_in[10];
  const float* att_b      = (const float*)d_in[11];
  const float* noise_f    = (const float*)d_in[12];
  const float* noise_m    = (const float*)d_in[13];
  float* out = (float*)d_out;

  f16*   whb = (f16*)d_ws;
  f16*   wxb = (f16*)((char*)d_ws + 131072);
  float* bp  = (float*)((char*)d_ws + 262144);

  idm_prep<<<256, 256, 0, stream>>>(lstm_Wx, lstm_Wh, lstm_b, att_W, whb, wxb, bp);
  idm_main<<<B_TOT / NB, 448, 0, stream>>>(z_att, linear_W, linear_b, sdv_acts,
                                           whb, wxb, bp,
                                           idm_params, idm_s, att_b,
                                           noise_f, noise_m, out);
}

// Round 6
// 175.744 us; speedup vs baseline: 1.0759x; 1.0157x over previous
//
#include <hip/hip_runtime.h>
#include <math.h>

// IDMForwardSim R12: R11b minus the unroll-2 pragma (it caused ~3.6MB of
// scratch spill traffic per dispatch, WRITE_SIZE 2560->6144 KB, eating the
// tail-in-loop gain) plus fused-reciprocal gate math: si*tg and so*tanh(cc)
// each collapse two rcp into one via rcp of a product (10 -> 8 trans ops per
// element on the dominant trans pipe; e2/d clamped at 1e30 so all overflow
// paths degenerate to correct 0, never NaN). R8 topology: NB=16, 448 thr,
// 7 waves, 2 blocks/CU; tail-in-loop on wave 0 lanes 0..15 at lag 2;
// exp2 constants pre-folded into weights (R11).

#define B_TOT 8192
#define T_STEPS 40
#define NB 16

typedef _Float16 f16;
typedef f16 f16x8 __attribute__((ext_vector_type(8)));
typedef float f32x4 __attribute__((ext_vector_type(4)));

__device__ __forceinline__ float rcpf(float x) { return __builtin_amdgcn_rcpf(x); }
__device__ __forceinline__ float ex2(float x)  { return __builtin_amdgcn_exp2f(x); }
__device__ __forceinline__ float sigf(float x)  { return rcpf(1.f + ex2(-1.44269504f * x)); }

// ws layout (bytes): whb f16[65536] @0 | wxb f16[65536] @131072 | bp f32[512] @262144

__global__ __launch_bounds__(256) void idm_prep(
    const float* __restrict__ Wx, const float* __restrict__ Wh,
    const float* __restrict__ bvec, const float* __restrict__ attw,
    f16* __restrict__ whb, f16* __restrict__ wxb,
    float* __restrict__ bp)
{
  int i = blockIdx.x * 256 + threadIdx.x;  // 0..65535, i = k*512 + n (coalesced reads)
  int k = i >> 9, n = i & 511;
  int g = n >> 7, j128 = n & 127;
  // pre-scale: sigmoid gates (zi,zf,zo) by log2(e), tanh gate (zg) by 2*log2(e)
  float sc = (g == 2) ? 2.88539008f : 1.44269504f;
  float vh = 0.f, vx = 0.f;
  if (j128 < 100) {
    int col = g * 100 + j128;
    if (k < 100)      { vh = Wh[k * 400 + col] * sc; vx = Wx[k * 400 + col] * sc; }
    else if (k < 102) { vh = Wx[k * 400 + col] * sc; }  // sdv rows folded into Wh-pad
  } else if (n == 100 && k < 100) {
    vh = attw[k];  // logit column stays UNSCALED (z[n=100] = h . att_W)
  }
  // dest B-frag index: tile=n>>4, kf=k>>5, l=((k>>3)&3)*16+(n&15), j=k&7
  int idx = (((n >> 4) * 4 + (k >> 5)) * 64 + (((k >> 3) & 3) * 16 + (n & 15))) * 8 + (k & 7);
  whb[idx] = (f16)vh;
  wxb[idx] = (f16)vx;
  if (i < 512) {
    int gg = i >> 7, jj = i & 127;
    float scb = (gg == 2) ? 2.88539008f : 1.44269504f;
    bp[i] = (jj < 100) ? bvec[gg * 100 + jj] * scb : 0.f;
  }
}

#define MM(z, a, g, kf) z = __builtin_amdgcn_mfma_f32_16x16x32_f16(a, wb[g][kf], z, 0, 0, 0)

// scratch-free tail step (wave 0, lanes 0..15; all state in plain locals)
#define TAIL_STEP(tt) {                                                        \
    int tt_ = (tt);                                                            \
    float2 s01 = *(const float2*)&sS[l][tt_][0];                               \
    float2 s23 = *(const float2*)&sS[l][tt_][2];                               \
    float2 s45 = *(const float2*)&sS[l][tt_][4];                               \
    float nf = nS[0][tt_][l], nm = nS[1][tt_][l];                              \
    float lg = attb + logitS[tt_][l];                                          \
    ego_v += actT * 0.1f;                                                      \
    ego_x += ego_v * 0.1f + actT * 0.005f;                                     \
    float dxf = fminf(fmaxf(s23.x - ego_x, 0.5f), 1000.f);                     \
    float dgf = min_jx + fmaxf(0.f, des_tg * ego_v + ego_v * (ego_v - s01.x) * inv2s); \
    float rr = ego_v * inv_dv; float rr2 = rr * rr;                            \
    float qf = dgf * rcpf(dxf);                                                \
    float af_ = fminf(fmaxf(max_a * (1.f - rr2 * rr2 - qf * qf), -3.f), 3.f);  \
    float dxm = fminf(fmaxf(s23.y - ego_x, 0.5f), 1000.f);                     \
    float dgm = min_jx + fmaxf(0.f, des_tg * ego_v + ego_v * (ego_v - s01.y) * inv2s); \
    float qm = dgm * rcpf(dxm);                                                \
    float am_ = fminf(fmaxf(max_a * (1.f - rr2 * rr2 - qm * qm), -3.f), 3.f);  \
    float ef2 = s45.x * af_ + (1.f - s45.x) * nf;                              \
    float em2 = s45.y * am_ + (1.f - s45.y) * nm;                              \
    float att = sigf(5.f * lg);                                                \
    actT = (1.f - att) * ef2 + att * em2;                                      \
    accS[0][l][tt_] = actT;                                                    \
    accS[1][l][tt_] = att;                                                     \
  }

__global__ __launch_bounds__(448, 4) void idm_main(
    const float* __restrict__ z_att,
    const float* __restrict__ linear_W,
    const float* __restrict__ linear_b,
    const float* __restrict__ sdv_acts,
    const f16* __restrict__ whb, const f16* __restrict__ wxb,
    const float* __restrict__ bp,
    const float* __restrict__ idm_params,
    const float* __restrict__ idm_s,
    const float* __restrict__ att_b,
    const float* __restrict__ noise_f,
    const float* __restrict__ noise_m,
    float* __restrict__ out)
{
  __shared__ f16   hS[2][16][136];       // [buf][batch][k] 0..99 h, 100..101 sdv, pad 0
  __shared__ f16   sdvS[T_STEPS][16][2];
  __shared__ float logitS[T_STEPS][16];
  __shared__ float sS[16][T_STEPS][6];   // idm_s fields 1,2,4,5,6,7
  __shared__ float nS[2][T_STEPS][16];   // noise_f / noise_m
  __shared__ float accS[2][16][T_STEPS]; // act, att

  const int tid = threadIdx.x;
  const int w  = tid >> 6;   // 0..6 j-tile
  const int l  = tid & 63;
  const int lr = l & 15;
  const int lq = l >> 4;
  const int b0g = blockIdx.x * NB;
  const int jcol = 16 * w + lr;
  const bool tail_lane = (tid < NB);  // wave 0, lanes 0..15

  // zero hS (pad rows must stay exact 0)
  for (int idx = tid; idx < 2176; idx += 448) ((unsigned*)hS)[idx] = 0u;
  // coalesced staging: sdv (1280 f), idm_s fields (5120 f), noise (1280 f)
  for (int idx = tid; idx < 1280; idx += 448) {
    float v = sdv_acts[(size_t)b0g * 80 + idx];
    int b = idx / 80, r = idx - b * 80;
    sdvS[r >> 1][b][r & 1] = (f16)v;
  }
  for (int idx = tid; idx < 5120; idx += 448) {
    int f = idx & 7;
    if (f != 0 && f != 3) {
      int b = idx / 320, rem = idx - b * 320, t = rem >> 3;
      sS[b][t][(f < 3) ? f - 1 : f - 2] = idm_s[(size_t)b0g * 320 + idx];
    }
  }
  for (int idx = tid; idx < 1280; idx += 448) {
    int which = idx >= 640 ? 1 : 0;
    int r = idx - which * 640;
    int t = r >> 4, i = r & 15;
    nS[which][t][i] = which ? noise_m[(size_t)t * B_TOT + b0g + i]
                            : noise_f[(size_t)t * B_TOT + b0g + i];
  }
  __syncthreads();

  // h0 = att_proj into hS[0]
  if (tid < 256) {
    int b = tid >> 4, oct = tid & 15;
    float za[10];
    #pragma unroll
    for (int t2 = 0; t2 < 10; ++t2) za[t2] = z_att[(b0g + b) * 10 + t2];
    #pragma unroll
    for (int jj = 0; jj < 8; ++jj) {
      int j = oct * 8 + jj;
      if (j < 100) {
        float acc = linear_b[j];
        #pragma unroll
        for (int t2 = 0; t2 < 10; ++t2) acc = fmaf(za[t2], linear_W[t2 * 100 + j], acc);
        hS[0][b][j] = (f16)acc;
      }
    }
  }
  if (tid < 32) hS[0][tid >> 1][100 + (tid & 1)] = sdvS[0][tid >> 1][tid & 1];
  __syncthreads();

  // Wx frags -> cx, then Wh frags (loop-invariant in regs)
  f16x8 wb[4][4];
  #pragma unroll
  for (int g = 0; g < 4; ++g) {
    int tile = w + 8 * g;
    #pragma unroll
    for (int kf = 0; kf < 4; ++kf)
      wb[g][kf] = *(const f16x8*)(wxb + ((size_t)(tile * 4 + kf) * 64 + l) * 8);
  }
  f32x4 cx[4];
  #pragma unroll
  for (int g = 0; g < 4; ++g) {
    float bpv = bp[(w + 8 * g) * 16 + lr];
    f32x4 c = {bpv, bpv, bpv, bpv};
    cx[g] = c;
  }
  #pragma unroll
  for (int kf = 0; kf < 4; ++kf) {
    f16x8 a = *(const f16x8*)(&hS[0][lr][kf * 32 + lq * 8]);
    #pragma unroll
    for (int g = 0; g < 4; ++g)
      cx[g] = __builtin_amdgcn_mfma_f32_16x16x32_f16(a, wb[g][kf], cx[g], 0, 0, 0);
  }
  #pragma unroll
  for (int g = 0; g < 4; ++g) {
    int tile = w + 8 * g;
    #pragma unroll
    for (int kf = 0; kf < 4; ++kf)
      wb[g][kf] = *(const f16x8*)(whb + ((size_t)(tile * 4 + kf) * 64 + l) * 8);
  }

  float cst[4];
  #pragma unroll
  for (int r = 0; r < 4; ++r) cst[r] = (float)hS[0][lq * 4 + r][jcol];

  // tail state (wave 0 lanes 0..15 only; plain locals, no lambda/scratch)
  float des_v = 1.f, des_tg = 0.f, min_jx = 0.f, max_a = 1.f;
  float inv2s = 0.f, inv_dv = 1.f, ego_v = 0.f, ego_x = 0.f, attb = 0.f, actT = 0.f;
  if (tail_lane) {
    int b = b0g + l;
    const float* P = idm_params + (size_t)b * 5;
    des_v = P[0]; des_tg = P[1]; min_jx = P[2]; max_a = P[3];
    inv2s = 0.5f / sqrtf(max_a * P[4]);
    inv_dv = rcpf(des_v);
    ego_v = idm_s[(size_t)b * 320 + 0];
    ego_x = idm_s[(size_t)b * 320 + 3];
    attb = att_b[0];
  }

  int p = 0;
  for (int t = 0; t < T_STEPS; ++t) {
    // A-frags for [h^{(t)}, sdv_t]
    f16x8 a0 = *(const f16x8*)(&hS[p][lr][0  + lq * 8]);
    f16x8 a1 = *(const f16x8*)(&hS[p][lr][32 + lq * 8]);
    f16x8 a2 = *(const f16x8*)(&hS[p][lr][64 + lq * 8]);
    f16x8 a3 = *(const f16x8*)(&hS[p][lr][96 + lq * 8]);
    f32x4 z0 = cx[0], z1 = cx[1], z2 = cx[2], z3 = cx[3];
    MM(z0,a0,0,0); MM(z1,a0,1,0); MM(z2,a0,2,0); MM(z3,a0,3,0);
    MM(z0,a1,0,1); MM(z1,a1,1,1); MM(z2,a1,2,1); MM(z3,a1,3,1);
    MM(z0,a2,0,2); MM(z1,a2,1,2); MM(z2,a2,2,2); MM(z3,a2,3,2);
    MM(z0,a3,0,3); MM(z1,a3,1,3); MM(z2,a3,2,3); MM(z3,a3,3,3);

    // logit for output t-1: z col n=100 (tile 6 = wave 6 g=0, lane lr==4)
    if (w == 6 && t > 0 && lr == 4) {
      #pragma unroll
      for (int r = 0; r < 4; ++r) logitS[t - 1][lq * 4 + r] = z0[r];
    }

    // gates with fused reciprocals: si*tg = (e2-1)/((1+e0)(1+e2)),
    // so*tanh(cc) = (d-1)/((1+e3)(1+d)); e2,d clamped so overflow -> 0, no NaN.
    // 5 ex2 + 3 rcp per element (was 5+5). Scale constants pre-folded into z.
    #pragma unroll
    for (int r = 0; r < 4; ++r) {
      float e0 = ex2(-z0[r]);
      float e1 = ex2(-z1[r]);
      float e2 = fminf(ex2(z2[r]), 1e30f);
      float e3 = ex2(-z3[r]);
      float sf  = rcpf(1.f + e1);
      float itg = (e2 - 1.f) * rcpf((1.f + e0) * (1.f + e2));  // si*tg
      float cc  = fmaf(sf, cst[r], itg);
      float d   = fminf(ex2(2.88539008f * cc), 1e30f);
      float hh  = (d - 1.f) * rcpf((1.f + e3) * (1.f + d));    // so*tanh(cc)
      cst[r] = cc;
      if (jcol < 100) hS[p ^ 1][lq * 4 + r][jcol] = (f16)hh;
    }
    if (t + 1 < T_STEPS && tid < 32)
      hS[p ^ 1][tid >> 1][100 + (tid & 1)] = sdvS[t + 1][tid >> 1][tid & 1];
    // wave 0 lanes 0..15: lag-2 tail step (logit[t-2] visible since end of
    // step t-1); independent of this wave's gates, scheduler interleaves
    if (tail_lane && t >= 2) TAIL_STEP(t - 2);
    __syncthreads();  // single barrier per step
    p ^= 1;
  }

  // final logit (t = T-1) from h^{(T)} in hS[p]: 4 MFMA on wave 6's gate-0 tile
  if (w == 6) {
    f32x4 zL = {0.f, 0.f, 0.f, 0.f};
    #pragma unroll
    for (int kf = 0; kf < 4; ++kf) {
      f16x8 a = *(const f16x8*)(&hS[p][lr][kf * 32 + lq * 8]);
      zL = __builtin_amdgcn_mfma_f32_16x16x32_f16(a, wb[0][kf], zL, 0, 0, 0);
    }
    if (lr == 4) {
      #pragma unroll
      for (int r = 0; r < 4; ++r) logitS[T_STEPS - 1][lq * 4 + r] = zL[r];
    }
  }
  // tail step 38 runnable now (logit[38] visible since last loop barrier)
  if (tail_lane) TAIL_STEP(T_STEPS - 2);
  __syncthreads();
  if (tail_lane) TAIL_STEP(T_STEPS - 1);
  __syncthreads();

  // coalesced output store: 640 floats per output
  if (tid < 160) {
    f32x4 va = ((const f32x4*)&accS[0][0][0])[tid];
    f32x4 vt = ((const f32x4*)&accS[1][0][0])[tid];
    *(f32x4*)(out + (size_t)b0g * T_STEPS + tid * 4) = va;
    *(f32x4*)(out + (size_t)B_TOT * T_STEPS + (size_t)b0g * T_STEPS + tid * 4) = vt;
  }
}

extern "C" void kernel_launch(void* const* d_in, const int* in_sizes, int n_in,
                              void* d_out, int out_size, void* d_ws, size_t ws_size,
                              hipStream_t stream) {
  const float* z_att      = (const float*)d_in[0];
  const float* idm_params = (const float*)d_in[2];
  const float* idm_s      = (const float*)d_in[3];
  const float* sdv_acts   = (const float*)d_in[4];
  const float* linear_W   = (const float*)d_in[5];
  const float* linear_b   = (const float*)d_in[6];
  const float* lstm_Wx    = (const float*)d_in[7];
  const float* lstm_Wh    = (const float*)d_in[8];
  const float* lstm_b     = (const float*)d_in[9];
  const float* att_W      = (const float*)d_in[10];
  const float* att_b      = (const float*)d_in[11];
  const float* noise_f    = (const float*)d_in[12];
  const float* noise_m    = (const float*)d_in[13];
  float* out = (float*)d_out;

  f16*   whb = (f16*)d_ws;
  f16*   wxb = (f16*)((char*)d_ws + 131072);
  float* bp  = (float*)((char*)d_ws + 262144);

  idm_prep<<<256, 256, 0, stream>>>(lstm_Wx, lstm_Wh, lstm_b, att_W, whb, wxb, bp);
  idm_main<<<B_TOT / NB, 448, 0, stream>>>(z_att, linear_W, linear_b, sdv_acts,
                                           whb, wxb, bp,
                                           idm_params, idm_s, att_b,
                                           noise_f, noise_m, out);
}

// Round 7
// 174.795 us; speedup vs baseline: 1.0817x; 1.0054x over previous
//
#include <hip/hip_runtime.h>
#include <math.h>

// IDMForwardSim R13: kill the t-loop register spill (R12: WRITE_SIZE 4352KB vs
// 2560KB output = ~1.8MB scratch; gfx950 unified VGPR+AGPR file is at exactly
// the 128-reg/4-waves-per-EU budget, so the tail's ~10 live scalars spilled).
// Tail live state cut to 3 regs (ego_v, ego_x, actT):
//  - att_b folded into bp[100] in idm_prep (logit col bias slot, was 0);
//    final-logit zL seeded from bp instead of 0.
//  - 5 IDM params staged in LDS pS[5][16] (coalesced), inv_dv/inv2s
//    pre-transformed in place; tail reads them per step (conflict-free).
// Otherwise R12: NB=16, 448 thr, 7 waves, 2 blocks/CU, tail-in-loop lag 2 on
// wave 0, exp2 constants pre-folded into weights, fused-reciprocal gates.

#define B_TOT 8192
#define T_STEPS 40
#define NB 16

typedef _Float16 f16;
typedef f16 f16x8 __attribute__((ext_vector_type(8)));
typedef float f32x4 __attribute__((ext_vector_type(4)));

__device__ __forceinline__ float rcpf(float x) { return __builtin_amdgcn_rcpf(x); }
__device__ __forceinline__ float ex2(float x)  { return __builtin_amdgcn_exp2f(x); }
__device__ __forceinline__ float sigf(float x)  { return rcpf(1.f + ex2(-1.44269504f * x)); }

// ws layout (bytes): whb f16[65536] @0 | wxb f16[65536] @131072 | bp f32[512] @262144

__global__ __launch_bounds__(256) void idm_prep(
    const float* __restrict__ Wx, const float* __restrict__ Wh,
    const float* __restrict__ bvec, const float* __restrict__ attw,
    const float* __restrict__ attB,
    f16* __restrict__ whb, f16* __restrict__ wxb,
    float* __restrict__ bp)
{
  int i = blockIdx.x * 256 + threadIdx.x;  // 0..65535, i = k*512 + n (coalesced reads)
  int k = i >> 9, n = i & 511;
  int g = n >> 7, j128 = n & 127;
  // pre-scale: sigmoid gates (zi,zf,zo) by log2(e), tanh gate (zg) by 2*log2(e)
  float sc = (g == 2) ? 2.88539008f : 1.44269504f;
  float vh = 0.f, vx = 0.f;
  if (j128 < 100) {
    int col = g * 100 + j128;
    if (k < 100)      { vh = Wh[k * 400 + col] * sc; vx = Wx[k * 400 + col] * sc; }
    else if (k < 102) { vh = Wx[k * 400 + col] * sc; }  // sdv rows folded into Wh-pad
  } else if (n == 100 && k < 100) {
    vh = attw[k];  // logit column stays UNSCALED (z[n=100] = h . att_W)
  }
  // dest B-frag index: tile=n>>4, kf=k>>5, l=((k>>3)&3)*16+(n&15), j=k&7
  int idx = (((n >> 4) * 4 + (k >> 5)) * 64 + (((k >> 3) & 3) * 16 + (n & 15))) * 8 + (k & 7);
  whb[idx] = (f16)vh;
  wxb[idx] = (f16)vx;
  if (i < 512) {
    int gg = i >> 7, jj = i & 127;
    float scb = (gg == 2) ? 2.88539008f : 1.44269504f;
    // bp[100] carries att_b (logit column bias); other pad cols stay 0
    bp[i] = (jj < 100) ? bvec[gg * 100 + jj] * scb
                       : ((i == 100) ? attB[0] : 0.f);
  }
}

#define MM(z, a, g, kf) z = __builtin_amdgcn_mfma_f32_16x16x32_f16(a, wb[g][kf], z, 0, 0, 0)

// tail step (wave 0, lanes 0..15). Per-batch params read from LDS pS each
// step (frees 6 regs vs keeping them live across the t-loop — the unified
// VGPR+AGPR file is at the 128-reg budget and anything over spills).
#define TAIL_STEP(tt) {                                                        \
    int tt_ = (tt);                                                            \
    float inv_dv = pS[0][l], des_tg = pS[1][l], min_jx = pS[2][l];             \
    float max_a = pS[3][l], inv2s = pS[4][l];                                  \
    float2 s01 = *(const float2*)&sS[l][tt_][0];                               \
    float2 s23 = *(const float2*)&sS[l][tt_][2];                               \
    float2 s45 = *(const float2*)&sS[l][tt_][4];                               \
    float nf = nS[0][tt_][l], nm = nS[1][tt_][l];                              \
    float lg = logitS[tt_][l];                                                 \
    ego_v += actT * 0.1f;                                                      \
    ego_x += ego_v * 0.1f + actT * 0.005f;                                     \
    float dxf = fminf(fmaxf(s23.x - ego_x, 0.5f), 1000.f);                     \
    float dgf = min_jx + fmaxf(0.f, des_tg * ego_v + ego_v * (ego_v - s01.x) * inv2s); \
    float rr = ego_v * inv_dv; float rr2 = rr * rr;                            \
    float qf = dgf * rcpf(dxf);                                                \
    float af_ = fminf(fmaxf(max_a * (1.f - rr2 * rr2 - qf * qf), -3.f), 3.f);  \
    float dxm = fminf(fmaxf(s23.y - ego_x, 0.5f), 1000.f);                     \
    float dgm = min_jx + fmaxf(0.f, des_tg * ego_v + ego_v * (ego_v - s01.y) * inv2s); \
    float qm = dgm * rcpf(dxm);                                                \
    float am_ = fminf(fmaxf(max_a * (1.f - rr2 * rr2 - qm * qm), -3.f), 3.f);  \
    float ef2 = s45.x * af_ + (1.f - s45.x) * nf;                              \
    float em2 = s45.y * am_ + (1.f - s45.y) * nm;                              \
    float att = sigf(5.f * lg);                                                \
    actT = (1.f - att) * ef2 + att * em2;                                      \
    accS[0][l][tt_] = actT;                                                    \
    accS[1][l][tt_] = att;                                                     \
  }

__global__ __launch_bounds__(448, 4) void idm_main(
    const float* __restrict__ z_att,
    const float* __restrict__ linear_W,
    const float* __restrict__ linear_b,
    const float* __restrict__ sdv_acts,
    const f16* __restrict__ whb, const f16* __restrict__ wxb,
    const float* __restrict__ bp,
    const float* __restrict__ idm_params,
    const float* __restrict__ idm_s,
    const float* __restrict__ noise_f,
    const float* __restrict__ noise_m,
    float* __restrict__ out)
{
  __shared__ f16   hS[2][16][136];       // [buf][batch][k] 0..99 h, 100..101 sdv, pad 0
  __shared__ f16   sdvS[T_STEPS][16][2];
  __shared__ float logitS[T_STEPS][16];
  __shared__ float sS[16][T_STEPS][6];   // idm_s fields 1,2,4,5,6,7
  __shared__ float nS[2][T_STEPS][16];   // noise_f / noise_m
  __shared__ float accS[2][16][T_STEPS]; // act, att
  __shared__ float pS[5][16];            // inv_dv, des_tg, min_jx, max_a, inv2s

  const int tid = threadIdx.x;
  const int w  = tid >> 6;   // 0..6 j-tile
  const int l  = tid & 63;
  const int lr = l & 15;
  const int lq = l >> 4;
  const int b0g = blockIdx.x * NB;
  const int jcol = 16 * w + lr;
  const bool tail_lane = (tid < NB);  // wave 0, lanes 0..15

  // zero hS (pad rows must stay exact 0)
  for (int idx = tid; idx < 2176; idx += 448) ((unsigned*)hS)[idx] = 0u;
  // coalesced staging: sdv (1280 f), idm_s fields (5120 f), noise (1280 f)
  for (int idx = tid; idx < 1280; idx += 448) {
    float v = sdv_acts[(size_t)b0g * 80 + idx];
    int b = idx / 80, r = idx - b * 80;
    sdvS[r >> 1][b][r & 1] = (f16)v;
  }
  for (int idx = tid; idx < 5120; idx += 448) {
    int f = idx & 7;
    if (f != 0 && f != 3) {
      int b = idx / 320, rem = idx - b * 320, t = rem >> 3;
      sS[b][t][(f < 3) ? f - 1 : f - 2] = idm_s[(size_t)b0g * 320 + idx];
    }
  }
  for (int idx = tid; idx < 1280; idx += 448) {
    int which = idx >= 640 ? 1 : 0;
    int r = idx - which * 640;
    int t = r >> 4, i = r & 15;
    nS[which][t][i] = which ? noise_m[(size_t)t * B_TOT + b0g + i]
                            : noise_f[(size_t)t * B_TOT + b0g + i];
  }
  // params: 80 consecutive floats, coalesced; pS[j][b] = idm_params[(b0g+b)*5+j]
  if (tid < 80) pS[tid % 5][tid / 5] = idm_params[(size_t)b0g * 5 + tid];
  __syncthreads();

  // in-place transform: pS[0] -> 1/des_v, pS[4] -> 0.5/sqrt(max_a*min_a)
  if (tid < 16) {
    pS[0][tid] = rcpf(pS[0][tid]);
    pS[4][tid] = 0.5f / sqrtf(pS[3][tid] * pS[4][tid]);
  }

  // h0 = att_proj into hS[0]
  if (tid >= 64 && tid < 320) {
    int s2 = tid - 64;
    int b = s2 >> 4, oct = s2 & 15;
    float za[10];
    #pragma unroll
    for (int t2 = 0; t2 < 10; ++t2) za[t2] = z_att[(b0g + b) * 10 + t2];
    #pragma unroll
    for (int jj = 0; jj < 8; ++jj) {
      int j = oct * 8 + jj;
      if (j < 100) {
        float acc = linear_b[j];
        #pragma unroll
        for (int t2 = 0; t2 < 10; ++t2) acc = fmaf(za[t2], linear_W[t2 * 100 + j], acc);
        hS[0][b][j] = (f16)acc;
      }
    }
  }
  if (tid < 32) hS[0][tid >> 1][100 + (tid & 1)] = sdvS[0][tid >> 1][tid & 1];
  __syncthreads();

  // Wx frags -> cx, then Wh frags (loop-invariant in regs)
  f16x8 wb[4][4];
  #pragma unroll
  for (int g = 0; g < 4; ++g) {
    int tile = w + 8 * g;
    #pragma unroll
    for (int kf = 0; kf < 4; ++kf)
      wb[g][kf] = *(const f16x8*)(wxb + ((size_t)(tile * 4 + kf) * 64 + l) * 8);
  }
  f32x4 cx[4];
  #pragma unroll
  for (int g = 0; g < 4; ++g) {
    float bpv = bp[(w + 8 * g) * 16 + lr];
    f32x4 c = {bpv, bpv, bpv, bpv};
    cx[g] = c;
  }
  #pragma unroll
  for (int kf = 0; kf < 4; ++kf) {
    f16x8 a = *(const f16x8*)(&hS[0][lr][kf * 32 + lq * 8]);
    #pragma unroll
    for (int g = 0; g < 4; ++g)
      cx[g] = __builtin_amdgcn_mfma_f32_16x16x32_f16(a, wb[g][kf], cx[g], 0, 0, 0);
  }
  #pragma unroll
  for (int g = 0; g < 4; ++g) {
    int tile = w + 8 * g;
    #pragma unroll
    for (int kf = 0; kf < 4; ++kf)
      wb[g][kf] = *(const f16x8*)(whb + ((size_t)(tile * 4 + kf) * 64 + l) * 8);
  }

  float cst[4];
  #pragma unroll
  for (int r = 0; r < 4; ++r) cst[r] = (float)hS[0][lq * 4 + r][jcol];

  // tail recurrent state: the ONLY tail registers live across the t-loop
  float ego_v = 0.f, ego_x = 0.f, actT = 0.f;
  if (tail_lane) {
    ego_v = idm_s[(size_t)(b0g + l) * 320 + 0];
    ego_x = idm_s[(size_t)(b0g + l) * 320 + 3];
  }

  int p = 0;
  for (int t = 0; t < T_STEPS; ++t) {
    // A-frags for [h^{(t)}, sdv_t]
    f16x8 a0 = *(const f16x8*)(&hS[p][lr][0  + lq * 8]);
    f16x8 a1 = *(const f16x8*)(&hS[p][lr][32 + lq * 8]);
    f16x8 a2 = *(const f16x8*)(&hS[p][lr][64 + lq * 8]);
    f16x8 a3 = *(const f16x8*)(&hS[p][lr][96 + lq * 8]);
    f32x4 z0 = cx[0], z1 = cx[1], z2 = cx[2], z3 = cx[3];
    MM(z0,a0,0,0); MM(z1,a0,1,0); MM(z2,a0,2,0); MM(z3,a0,3,0);
    MM(z0,a1,0,1); MM(z1,a1,1,1); MM(z2,a1,2,1); MM(z3,a1,3,1);
    MM(z0,a2,0,2); MM(z1,a2,1,2); MM(z2,a2,2,2); MM(z3,a2,3,2);
    MM(z0,a3,0,3); MM(z1,a3,1,3); MM(z2,a3,2,3); MM(z3,a3,3,3);

    // logit for output t-1: z col n=100 (tile 6 = wave 6 g=0, lane lr==4);
    // includes att_b via bp[100] folded into cx
    if (w == 6 && t > 0 && lr == 4) {
      #pragma unroll
      for (int r = 0; r < 4; ++r) logitS[t - 1][lq * 4 + r] = z0[r];
    }

    // gates with fused reciprocals: si*tg = (e2-1)/((1+e0)(1+e2)),
    // so*tanh(cc) = (d-1)/((1+e3)(1+d)); e2,d clamped so overflow -> 0, no NaN.
    #pragma unroll
    for (int r = 0; r < 4; ++r) {
      float e0 = ex2(-z0[r]);
      float e1 = ex2(-z1[r]);
      float e2 = fminf(ex2(z2[r]), 1e30f);
      float e3 = ex2(-z3[r]);
      float sf  = rcpf(1.f + e1);
      float itg = (e2 - 1.f) * rcpf((1.f + e0) * (1.f + e2));  // si*tg
      float cc  = fmaf(sf, cst[r], itg);
      float d   = fminf(ex2(2.88539008f * cc), 1e30f);
      float hh  = (d - 1.f) * rcpf((1.f + e3) * (1.f + d));    // so*tanh(cc)
      cst[r] = cc;
      if (jcol < 100) hS[p ^ 1][lq * 4 + r][jcol] = (f16)hh;
    }
    if (t + 1 < T_STEPS && tid < 32)
      hS[p ^ 1][tid >> 1][100 + (tid & 1)] = sdvS[t + 1][tid >> 1][tid & 1];
    // wave 0 lanes 0..15: lag-2 tail step (logit[t-2] visible since end of
    // step t-1); independent of this wave's gates, scheduler interleaves
    if (tail_lane && t >= 2) TAIL_STEP(t - 2);
    __syncthreads();  // single barrier per step
    p ^= 1;
  }

  // final logit (t = T-1) from h^{(T)} in hS[p]: 4 MFMA on wave 6's gate-0
  // tile, seeded with bp (att_b at col 100)
  if (w == 6) {
    float bpv6 = bp[96 + lr];
    f32x4 zL = {bpv6, bpv6, bpv6, bpv6};
    #pragma unroll
    for (int kf = 0; kf < 4; ++kf) {
      f16x8 a = *(const f16x8*)(&hS[p][lr][kf * 32 + lq * 8]);
      zL = __builtin_amdgcn_mfma_f32_16x16x32_f16(a, wb[0][kf], zL, 0, 0, 0);
    }
    if (lr == 4) {
      #pragma unroll
      for (int r = 0; r < 4; ++r) logitS[T_STEPS - 1][lq * 4 + r] = zL[r];
    }
  }
  // tail step 38 runnable now (logit[38] visible since last loop barrier)
  if (tail_lane) TAIL_STEP(T_STEPS - 2);
  __syncthreads();
  if (tail_lane) TAIL_STEP(T_STEPS - 1);
  __syncthreads();

  // coalesced output store: 640 floats per output
  if (tid < 160) {
    f32x4 va = ((const f32x4*)&accS[0][0][0])[tid];
    f32x4 vt = ((const f32x4*)&accS[1][0][0])[tid];
    *(f32x4*)(out + (size_t)b0g * T_STEPS + tid * 4) = va;
    *(f32x4*)(out + (size_t)B_TOT * T_STEPS + (size_t)b0g * T_STEPS + tid * 4) = vt;
  }
}

extern "C" void kernel_launch(void* const* d_in, const int* in_sizes, int n_in,
                              void* d_out, int out_size, void* d_ws, size_t ws_size,
                              hipStream_t stream) {
  const float* z_att      = (const float*)d_in[0];
  const float* idm_params = (const float*)d_in[2];
  const float* idm_s      = (const float*)d_in[3];
  const float* sdv_acts   = (const float*)d_in[4];
  const float* linear_W   = (const float*)d_in[5];
  const float* linear_b   = (const float*)d_in[6];
  const float* lstm_Wx    = (const float*)d_in[7];
  const float* lstm_Wh    = (const float*)d_in[8];
  const float* lstm_b     = (const float*)d_in[9];
  const float* att_W      = (const float*)d_in[10];
  const float* att_b      = (const float*)d_in[11];
  const float* noise_f    = (const float*)d_in[12];
  const float* noise_m    = (const float*)d_in[13];
  float* out = (float*)d_out;

  f16*   whb = (f16*)d_ws;
  f16*   wxb = (f16*)((char*)d_ws + 131072);
  float* bp  = (float*)((char*)d_ws + 262144);

  idm_prep<<<256, 256, 0, stream>>>(lstm_Wx, lstm_Wh, lstm_b, att_W, att_b,
                                    whb, wxb, bp);
  idm_main<<<B_TOT / NB, 448, 0, stream>>>(z_att, linear_W, linear_b, sdv_acts,
                                           whb, wxb, bp,
                                           idm_params, idm_s,
                                           noise_f, noise_m, out);
}